// Round 9
// baseline (179.793 us; speedup 1.0000x reference)
//
#include <hip/hip_runtime.h>
#include <hip/hip_bf16.h>

// Problem constants
#define BB    16
#define TT    784
#define TPK   832          // padded T for K/V (13*64)
#define TPQ   896          // padded T for Q
#define EE    512
#define HH    8
#define DD    64
#define BT    (BB*TT)      // 12544 = 98*128

typedef short short8 __attribute__((ext_vector_type(8)));
typedef short short4v __attribute__((ext_vector_type(4)));
typedef float floatx4 __attribute__((ext_vector_type(4)));
typedef float floatx16 __attribute__((ext_vector_type(16)));
typedef unsigned uint4v __attribute__((ext_vector_type(4)));

__device__ __forceinline__ short f2bf(float f) {
    unsigned u = __builtin_bit_cast(unsigned, f);
    u += 0x7FFFu + ((u >> 16) & 1u);   // round-to-nearest-even
    return (short)(u >> 16);
}

__device__ __forceinline__ unsigned cvtpk_bf16(float lo, float hi) {
    unsigned r;
    asm("v_cvt_pk_bf16_f32 %0, %1, %2" : "=v"(r) : "v"(lo), "v"(hi));
    return r;
}

// async global->LDS DMA, 16B per lane; LDS dest = wave-uniform base + lane*16
__device__ __forceinline__ void gload_lds16(const short* g, short* l) {
    __builtin_amdgcn_global_load_lds(
        (const __attribute__((address_space(1))) void*)g,
        (__attribute__((address_space(3))) void*)l, 16, 0, 0);
}

// ---------------- merged prep: cast_x | pack Wqkv^T | pack Wo^T | zero pads ------------
__global__ void prep_kernel(const float* __restrict__ x, short* __restrict__ xb,
                            const float* __restrict__ Wq, const float* __restrict__ Wk,
                            const float* __restrict__ Wv, short* __restrict__ wqkvt,
                            const float* __restrict__ Wo, short* __restrict__ wot,
                            short* __restrict__ Qb, short* __restrict__ Kb, short* __restrict__ Vt)
{
    __shared__ short t[64][65];
    int b = blockIdx.x;
    if (b < 3136) {
        int i = (b * 256 + threadIdx.x) * 8;
        float4 a = *(const float4*)(x + i);
        float4 c = *(const float4*)(x + i + 4);
        short8 o;
        o[0] = f2bf(a.x); o[1] = f2bf(a.y); o[2] = f2bf(a.z); o[3] = f2bf(a.w);
        o[4] = f2bf(c.x); o[5] = f2bf(c.y); o[6] = f2bf(c.z); o[7] = f2bf(c.w);
        *(short8*)(xb + i) = o;
    } else if (b < 3392) {
        const float* W; short* out; int n0, k0;
        if (b < 3328) {
            int tt = b - 3136;               // 0..191
            n0 = (tt % 24) * 64; k0 = (tt / 24) * 64;
            W = (n0 < 512) ? Wq : (n0 < 1024 ? Wk : Wv);
            out = wqkvt;
        } else {
            int tt = b - 3328;               // 0..63
            n0 = (tt % 8) * 64; k0 = (tt / 8) * 64;
            W = Wo; out = wot;
        }
        int nn0 = n0 & 511;
        for (int i = threadIdx.x; i < 4096; i += 256) {
            int r = i >> 6, c = i & 63;
            t[r][c] = f2bf(W[(k0 + r) * 512 + nn0 + c]);
        }
        __syncthreads();
        for (int i = threadIdx.x; i < 4096; i += 256) {
            int nr = i >> 6, kc = i & 63;
            out[(n0 + nr) * 512 + k0 + kc] = t[kc][nr];
        }
    } else {
        // zero pads as short8 chunks: Q rows [784,896), K rows [784,832), Vt cols [784,832)
        int c = (b - 3392) * 256 + threadIdx.x;   // 0..212991
        short8 z = (short8){0,0,0,0,0,0,0,0};
        if (c < 114688) {                          // Q: 896 chunks per bh
            int bh = c / 896, j = c - bh * 896;
            *(short8*)&Qb[(bh * TPQ + TT) * 64 + j * 8] = z;
        } else if (c < 163840) {                   // K: 384 chunks per bh
            int c2 = c - 114688;
            int bh = c2 / 384, j = c2 - bh * 384;
            *(short8*)&Kb[(bh * TPK + TT) * 64 + j * 8] = z;
        } else {                                   // Vt: 384 chunks per bh (6 per d-row)
            int c3 = c - 163840;
            int bh = c3 / 384, j = c3 - bh * 384;
            int d = j / 6, m = j - d * 6;
            *(short8*)&Vt[(bh * 64 + d) * TPK + TT + m * 8] = z;
        }
    }
}

// ---------------- GEMM1: 128x128 tiles, 3-deep counted-vmcnt pipeline ----------------
// R8 PMC validated: FETCH 146->13.1 MB (ideal), bank conflicts 16.9M->401K, dur
// 82->53 us under rocprof. Keep unchanged this round (stability check).
__global__ __launch_bounds__(256, 3) void gemm_qkv_kernel(
    const short* __restrict__ A, const short* __restrict__ Bt,
    const float* __restrict__ bq, const float* __restrict__ bk, const float* __restrict__ bv,
    short* __restrict__ Qb, short* __restrict__ Kb, short* __restrict__ Vt)
{
    __shared__ __align__(16) short smem[24576];   // A [3][4096] + B [3][4096]; Ct reuses
    short* As0 = smem;
    short* Bs0 = smem + 12288;

    const int orig = blockIdx.x;
    const int tile = (orig & 7) * 147 + (orig >> 3);   // bijective XCD chunk (1176=8*147)
    const int m0 = (tile / 12) * 128, n0 = (tile % 12) * 128;  // n-fastest: A-tile reuse
    const int tid = threadIdx.x;
    const int lane = tid & 63, w = tid >> 6;
    const int wr = w >> 1, wc = w & 1;
    const int l16 = lane & 15, quad = lane >> 4;

    const int sr = tid & 127;            // row 0..127
    const int sc = tid >> 7;             // k-granule 0/1 (second load: +2)
    const short* Ag = A  + (size_t)(m0 + sr) * 512 + sc * 8;
    const short* Bg = Bt + (size_t)(n0 + sr) * 512 + sc * 8;

    auto stage = [&](int it) {
        int b = it % 3;
        int ko = it * 32;
        gload_lds16(Ag + ko,      As0 + b * 4096 + tid * 8);
        gload_lds16(Ag + ko + 16, As0 + b * 4096 + 2048 + tid * 8);
        gload_lds16(Bg + ko,      Bs0 + b * 4096 + tid * 8);
        gload_lds16(Bg + ko + 16, Bs0 + b * 4096 + 2048 + tid * 8);
    };

    floatx4 acc[4][4];
    #pragma unroll
    for (int i = 0; i < 4; i++)
        #pragma unroll
        for (int j = 0; j < 4; j++)
            acc[i][j] = (floatx4){0.f, 0.f, 0.f, 0.f};

    stage(0);
    stage(1);

    #pragma unroll
    for (int it = 0; it < 16; it++) {
        if (it < 15) asm volatile("s_waitcnt vmcnt(4)" ::: "memory");
        else         asm volatile("s_waitcnt vmcnt(0)" ::: "memory");
        __builtin_amdgcn_s_barrier();
        __builtin_amdgcn_sched_barrier(0);
        if (it < 14) stage(it + 2);            // overwrites buf (it-1)%3: reads consumed
        const short* as = As0 + (it % 3) * 4096;
        const short* bs = Bs0 + (it % 3) * 4096;
        short8 af[4], bf[4];
        #pragma unroll
        for (int i = 0; i < 4; i++) {
            af[i] = *(const short8*)&as[quad * 1024 + (wr * 64 + i * 16 + l16) * 8];
            bf[i] = *(const short8*)&bs[quad * 1024 + (wc * 64 + i * 16 + l16) * 8];
        }
        #pragma unroll
        for (int mi = 0; mi < 4; mi++)
            #pragma unroll
            for (int ni = 0; ni < 4; ni++)
                acc[mi][ni] = __builtin_amdgcn_mfma_f32_16x16x32_bf16(af[mi], bf[ni], acc[mi][ni], 0, 0, 0);
    }
    __syncthreads();

    const int sel = n0 >> 9;   // 0=Q, 1=K, 2=V (uniform per block)
    if (sel == 2) {
        #pragma unroll
        for (int mi = 0; mi < 4; mi++) {
            int m = m0 + wr * 64 + mi * 16 + quad * 4;
            int bb = m / TT, t = m - bb * TT;
            #pragma unroll
            for (int ni = 0; ni < 4; ni++) {
                int nn = (n0 + wc * 64 + ni * 16 + l16) & 511;
                int hh = nn >> 6, dd = nn & 63;
                float b = bv[nn];
                short4v pv;
                #pragma unroll
                for (int r = 0; r < 4; r++) pv[r] = f2bf(acc[mi][ni][r] + b);
                *(short4v*)&Vt[((size_t)(bb * HH + hh) * 64 + dd) * TPK + t] = pv;
            }
        }
    } else {
        short* Ct = smem;  // [128][130] bf16
        const float* bias = (sel == 0) ? bq : bk;
        #pragma unroll
        for (int mi = 0; mi < 4; mi++) {
            #pragma unroll
            for (int ni = 0; ni < 4; ni++) {
                int nl = wc * 64 + ni * 16 + l16;
                int nn = (n0 + nl) & 511;
                float b = bias[nn];
                #pragma unroll
                for (int r = 0; r < 4; r++) {
                    float v = acc[mi][ni][r] + b;
                    if (sel == 0) v *= 0.125f;
                    Ct[(wr * 64 + mi * 16 + quad * 4 + r) * 130 + nl] = f2bf(v);
                }
            }
        }
        __syncthreads();
        short* dst = (sel == 0) ? Qb : Kb;
        const int tp = (sel == 0) ? TPQ : TPK;
        int nl = lane * 2;
        int nn = (n0 + nl) & 511;
        int hh = nn >> 6, dd = nn & 63;
        #pragma unroll 4
        for (int rr = 0; rr < 32; rr++) {
            int ml = w * 32 + rr;
            int m = m0 + ml;
            int bb = m / TT, t = m - bb * TT;
            unsigned pv = *(const unsigned*)&Ct[ml * 130 + nl];
            *(unsigned*)&dst[((bb * HH + hh) * tp + t) * 64 + dd] = pv;
        }
    }
}

// ---------------- attention: 128-q blocks, each wave owns 32 q, full key range -------
// vs R6: 896 blocks (was 1664); per unit q-work HALF the staging traffic, HALF the
// barriers; no k-split -> no end LDS reduction. Wave w owns q [q0+32w, q0+32w+32);
// kh loop (0/1) replaces the old wk wave-split; all verified swizzles/masks reused.
__global__ __launch_bounds__(256, 3) void attn_kernel(
    const short* __restrict__ Qb, const short* __restrict__ Kb, const short* __restrict__ Vt,
    short* __restrict__ ctx)
{
    // id = ((6-qb)*16 + bb)*8 + hh -> hh pins (b,h) to one XCD; qb descending = LPT
    const int g = blockIdx.x;
    const int low = g & 7, rest = g >> 3;
    const int qb = 6 - (rest >> 4);           // q-block 0..6 (128 rows each)
    const int bh = ((rest & 15) << 3) | low;
    const int bb = bh >> 3, hh = bh & 7;
    const int tid = threadIdx.x;
    const int lane = tid & 63, w = tid >> 6;
    const int l32 = lane & 31, hi = lane >> 5;
    const int r7 = l32 & 7;

    __shared__ __align__(16) short Ks[2][4096];   // [key][d], granule-XOR swizzle
    __shared__ __align__(16) short Vs[2][4096];   // [d][sigma(key)], granule-XOR swizzle

    const short* Kbase = Kb + (size_t)(bh * TPK) * 64;
    const short* Vbase = Vt + (size_t)(bh * 64) * TPK;

    const int srow = tid >> 3;          // 0..31
    const int sc8  = tid & 7;
    const int scol = sc8 * 8;
    const int ksw  = (sc8 ^ (srow & 7)) * 8;
    const int vg0  = (sc8 >> 1) * 2;
    const int vsw0 = ((vg0       ^ (srow & 7)) * 8) + (sc8 & 1) * 4;
    const int vsw1 = (((vg0 + 1) ^ (srow & 7)) * 8) + (sc8 & 1) * 4;

    short8 kreg[2], vreg[2];
    auto load_tile = [&](int kt) {
        #pragma unroll
        for (int p = 0; p < 2; p++) {
            int row = srow + p * 32;
            kreg[p] = *(const short8*)(Kbase + (kt * 64 + row) * 64 + scol);
            vreg[p] = *(const short8*)(Vbase + row * TPK + kt * 64 + scol);
        }
    };
    auto store_tile = [&](int b) {
        #pragma unroll
        for (int p = 0; p < 2; p++) {
            int ro = (srow + p * 32) * 64;
            *(short8*)&Ks[b][ro + ksw] = kreg[p];
            short4v v0, v1;
            #pragma unroll
            for (int i = 0; i < 4; i++) { v0[i] = vreg[p][i]; v1[i] = vreg[p][i + 4]; }
            *(short4v*)&Vs[b][ro + vsw0] = v0;
            *(short4v*)&Vs[b][ro + vsw1] = v1;
        }
    };

    const int q0   = qb * 128;
    const int q_lo = q0 + w * 32;                 // this wave's lowest q
    const int qg   = q_lo + l32;                  // this lane's q row (may be pad)
    const bool wreal = (q_lo < TT);
    // k-tiles needed by the block: up to the highest REAL q row in the block
    const int q_top = (q0 + 127 < TT - 1) ? (q0 + 127) : (TT - 1);
    const int KT = (q_top >> 6) + 1;              // 2*qb+2, or 13 for qb=6

    const short* Qrow = Qb + (size_t)(bh * TPQ + qg) * 64;
    short8 qf[4];
    #pragma unroll
    for (int d = 0; d < 4; d++) qf[d] = *(const short8*)(Qrow + d * 16 + hi * 8);

    floatx16 accO[2];
    #pragma unroll
    for (int dt = 0; dt < 2; dt++)
        #pragma unroll
        for (int i = 0; i < 16; i++) accO[dt][i] = 0.f;
    float accL = 0.f;

    load_tile(0);
    store_tile(0);

    for (int kt = 0; kt < KT; kt++) {
        const int cb = kt & 1;
        if (kt < KT - 1) load_tile(kt + 1);   // prefetch into regs, overlapped
        __syncthreads();                       // staging for kt visible
        if (wreal) {
            #pragma unroll
            for (int kh = 0; kh < 2; kh++) {
                const int kbase = kt * 64 + kh * 32;
                if (kbase > q_lo + 31) continue;   // wave-uniform: fully masked half
                floatx16 z;
                #pragma unroll
                for (int i = 0; i < 16; i++) z[i] = 0.f;
                #pragma unroll
                for (int d = 0; d < 4; d++) {
                    short8 kf = *(const short8*)&Ks[cb][(kh * 32 + l32) * 64 + (((d * 2 + hi) ^ r7) * 8)];
                    z = __builtin_amdgcn_mfma_f32_32x32x16_bf16(kf, qf[d], z, 0, 0, 0);
                }
                float p[16];
                #pragma unroll
                for (int r = 0; r < 16; r++) p[r] = __expf(z[r]);
                if (kbase + 31 > q_lo) {          // partial: causal mask (kills pad keys too)
                    #pragma unroll
                    for (int r = 0; r < 16; r++) {
                        int keyg = kbase + (r & 3) + 8 * (r >> 2) + 4 * hi;
                        if (keyg > qg) p[r] = 0.f;
                    }
                }
                #pragma unroll
                for (int r = 0; r < 16; r++) accL += p[r];
                #pragma unroll
                for (int s = 0; s < 2; s++) {
                    uint4v pw;
                    #pragma unroll
                    for (int jj = 0; jj < 4; jj++)
                        pw[jj] = cvtpk_bf16(p[8 * s + 2 * jj], p[8 * s + 2 * jj + 1]);
                    short8 pb = __builtin_bit_cast(short8, pw);
                    #pragma unroll
                    for (int dt = 0; dt < 2; dt++) {
                        short8 vf = *(const short8*)&Vs[cb][(dt * 32 + l32) * 64 + (((kh * 4 + s * 2 + hi) ^ r7) * 8)];
                        accO[dt] = __builtin_amdgcn_mfma_f32_32x32x16_bf16(vf, pb, accO[dt], 0, 0, 0);
                    }
                }
            }
        }
        if (kt < KT - 1) store_tile((kt + 1) & 1);   // all waves past this iter's barrier
    }

    // epilogue: combine hi-halves' row sums (lanes l32 / l32+32 share q), normalize, store
    float Lt = accL + __shfl_xor(accL, 32, 64);
    if (wreal && qg < TT) {
        float inv = 1.f / Lt;
        short* crow = ctx + (size_t)(bb * TT + qg) * 512 + hh * 64;
        #pragma unroll
        for (int dt = 0; dt < 2; dt++)
            #pragma unroll
            for (int g4 = 0; g4 < 4; g4++) {
                short4v pv;
                #pragma unroll
                for (int r4 = 0; r4 < 4; r4++) pv[r4] = f2bf(accO[dt][g4 * 4 + r4] * inv);
                *(short4v*)&crow[dt * 32 + g4 * 8 + 4 * hi] = pv;
            }
    }
}

// ---------------- GEMM2: ctx @ Wo + bo, 3-deep counted-vmcnt pipeline ----------------
// Same structure as gemm_qkv (R8 PMC-validated): plane layout + vmcnt(4) + s_barrier.
__global__ __launch_bounds__(256, 3) void gemm_out_kernel(
    const short* __restrict__ A, const short* __restrict__ Bt,
    const float* __restrict__ bo, float* __restrict__ out)
{
    __shared__ __align__(16) short smem[24576];
    short* As0 = smem;
    short* Bs0 = smem + 12288;

    const int orig = blockIdx.x;
    const int tile = (orig & 7) * 49 + (orig >> 3);    // 392 = 8*49, bijective
    const int m0 = (tile >> 2) * 128, n0 = (tile & 3) * 128;  // n fastest: ctx reuse
    const int tid = threadIdx.x;
    const int lane = tid & 63, w = tid >> 6;
    const int wr = w >> 1, wc = w & 1;
    const int l16 = lane & 15, quad = lane >> 4;

    const int sr = tid & 127;
    const int sc = tid >> 7;
    const short* Ag = A  + (size_t)(m0 + sr) * 512 + sc * 8;
    const short* Bg = Bt + (size_t)(n0 + sr) * 512 + sc * 8;

    auto stage = [&](int it) {
        int b = it % 3;
        int ko = it * 32;
        gload_lds16(Ag + ko,      As0 + b * 4096 + tid * 8);
        gload_lds16(Ag + ko + 16, As0 + b * 4096 + 2048 + tid * 8);
        gload_lds16(Bg + ko,      Bs0 + b * 4096 + tid * 8);
        gload_lds16(Bg + ko + 16, Bs0 + b * 4096 + 2048 + tid * 8);
    };

    floatx4 acc[4][4];
    #pragma unroll
    for (int i = 0; i < 4; i++)
        #pragma unroll
        for (int j = 0; j < 4; j++)
            acc[i][j] = (floatx4){0.f, 0.f, 0.f, 0.f};

    stage(0);
    stage(1);

    #pragma unroll
    for (int it = 0; it < 16; it++) {
        if (it < 15) asm volatile("s_waitcnt vmcnt(4)" ::: "memory");
        else         asm volatile("s_waitcnt vmcnt(0)" ::: "memory");
        __builtin_amdgcn_s_barrier();
        __builtin_amdgcn_sched_barrier(0);
        if (it < 14) stage(it + 2);
        const short* as = As0 + (it % 3) * 4096;
        const short* bs = Bs0 + (it % 3) * 4096;
        short8 af[4], bf[4];
        #pragma unroll
        for (int i = 0; i < 4; i++) {
            af[i] = *(const short8*)&as[quad * 1024 + (wr * 64 + i * 16 + l16) * 8];
            bf[i] = *(const short8*)&bs[quad * 1024 + (wc * 64 + i * 16 + l16) * 8];
        }
        #pragma unroll
        for (int mi = 0; mi < 4; mi++)
            #pragma unroll
            for (int ni = 0; ni < 4; ni++)
                acc[mi][ni] = __builtin_amdgcn_mfma_f32_16x16x32_bf16(af[mi], bf[ni], acc[mi][ni], 0, 0, 0);
    }

    #pragma unroll
    for (int mi = 0; mi < 4; mi++) {
        #pragma unroll
        for (int ni = 0; ni < 4; ni++) {
            int n = n0 + wc * 64 + ni * 16 + l16;
            float bias = bo[n];
            #pragma unroll
            for (int r = 0; r < 4; r++) {
                int m = m0 + wr * 64 + mi * 16 + quad * 4 + r;
                out[(size_t)m * 512 + n] = acc[mi][ni][r] + bias;
            }
        }
    }
}

extern "C" void kernel_launch(void* const* d_in, const int* in_sizes, int n_in,
                              void* d_out, int out_size, void* d_ws, size_t ws_size,
                              hipStream_t stream) {
    const float* x  = (const float*)d_in[0];
    const float* Wq = (const float*)d_in[1];
    const float* bq = (const float*)d_in[2];
    const float* Wk = (const float*)d_in[3];
    const float* bk = (const float*)d_in[4];
    const float* Wv = (const float*)d_in[5];
    const float* bv = (const float*)d_in[6];
    const float* Wo = (const float*)d_in[7];
    const float* bo = (const float*)d_in[8];
    float* out = (float*)d_out;

    char* ws = (char*)d_ws;
    size_t off = 0;
    auto alloc = [&](size_t bytes) -> void* {
        void* p = ws + off;
        off += (bytes + 255) & ~(size_t)255;
        return p;
    };
    short* xb    = (short*)alloc((size_t)BT * EE * 2);        // x bf16
    short* wqkvt = (short*)alloc((size_t)1536 * 512 * 2);     // Wqkv^T bf16
    short* wot   = (short*)alloc((size_t)512 * 512 * 2);      // Wo^T bf16
    short* Qb    = (short*)alloc((size_t)BB * HH * TPQ * DD * 2);
    short* Kb    = (short*)alloc((size_t)BB * HH * TPK * DD * 2);
    short* Vtb   = (short*)alloc((size_t)BB * HH * DD * TPK * 2);
    short* ctxb  = (short*)alloc((size_t)BT * EE * 2);

    prep_kernel<<<4224, 256, 0, stream>>>(x, xb, Wq, Wk, Wv, wqkvt, Wo, wot, Qb, Kb, Vtb);
    gemm_qkv_kernel<<<1176, 256, 0, stream>>>(xb, wqkvt, bq, bk, bv, Qb, Kb, Vtb);
    attn_kernel<<<896, 256, 0, stream>>>(Qb, Kb, Vtb, ctxb);
    gemm_out_kernel<<<392, 256, 0, stream>>>(ctxb, wot, bo, out);
}

// Round 10
// 158.071 us; speedup vs baseline: 1.1374x; 1.1374x over previous
//
#include <hip/hip_runtime.h>
#include <hip/hip_bf16.h>

// Problem constants
#define BB    16
#define TT    784
#define TPK   832          // padded T for K/V (13*64)
#define TPQ   896          // padded T for Q
#define EE    512
#define HH    8
#define DD    64
#define BT    (BB*TT)      // 12544 = 98*128

typedef short short8 __attribute__((ext_vector_type(8)));
typedef short short4v __attribute__((ext_vector_type(4)));
typedef float floatx4 __attribute__((ext_vector_type(4)));
typedef float floatx16 __attribute__((ext_vector_type(16)));
typedef unsigned uint4v __attribute__((ext_vector_type(4)));

__device__ __forceinline__ short f2bf(float f) {
    unsigned u = __builtin_bit_cast(unsigned, f);
    u += 0x7FFFu + ((u >> 16) & 1u);   // round-to-nearest-even
    return (short)(u >> 16);
}

__device__ __forceinline__ unsigned cvtpk_bf16(float lo, float hi) {
    unsigned r;
    asm("v_cvt_pk_bf16_f32 %0, %1, %2" : "=v"(r) : "v"(lo), "v"(hi));
    return r;
}

// async global->LDS DMA, 16B per lane; LDS dest = wave-uniform base + lane*16
__device__ __forceinline__ void gload_lds16(const short* g, short* l) {
    __builtin_amdgcn_global_load_lds(
        (const __attribute__((address_space(1))) void*)g,
        (__attribute__((address_space(3))) void*)l, 16, 0, 0);
}

// ---------------- merged prep: cast_x | pack Wqkv^T | pack Wo^T | zero pads ------------
__global__ void prep_kernel(const float* __restrict__ x, short* __restrict__ xb,
                            const float* __restrict__ Wq, const float* __restrict__ Wk,
                            const float* __restrict__ Wv, short* __restrict__ wqkvt,
                            const float* __restrict__ Wo, short* __restrict__ wot,
                            short* __restrict__ Qb, short* __restrict__ Kb, short* __restrict__ Vt)
{
    __shared__ short t[64][65];
    int b = blockIdx.x;
    if (b < 3136) {
        int i = (b * 256 + threadIdx.x) * 8;
        float4 a = *(const float4*)(x + i);
        float4 c = *(const float4*)(x + i + 4);
        short8 o;
        o[0] = f2bf(a.x); o[1] = f2bf(a.y); o[2] = f2bf(a.z); o[3] = f2bf(a.w);
        o[4] = f2bf(c.x); o[5] = f2bf(c.y); o[6] = f2bf(c.z); o[7] = f2bf(c.w);
        *(short8*)(xb + i) = o;
    } else if (b < 3392) {
        const float* W; short* out; int n0, k0;
        if (b < 3328) {
            int tt = b - 3136;               // 0..191
            n0 = (tt % 24) * 64; k0 = (tt / 24) * 64;
            W = (n0 < 512) ? Wq : (n0 < 1024 ? Wk : Wv);
            out = wqkvt;
        } else {
            int tt = b - 3328;               // 0..63
            n0 = (tt % 8) * 64; k0 = (tt / 8) * 64;
            W = Wo; out = wot;
        }
        int nn0 = n0 & 511;
        for (int i = threadIdx.x; i < 4096; i += 256) {
            int r = i >> 6, c = i & 63;
            t[r][c] = f2bf(W[(k0 + r) * 512 + nn0 + c]);
        }
        __syncthreads();
        for (int i = threadIdx.x; i < 4096; i += 256) {
            int nr = i >> 6, kc = i & 63;
            out[(n0 + nr) * 512 + k0 + kc] = t[kc][nr];
        }
    } else {
        // zero pads as short8 chunks: Q rows [784,896), K rows [784,832), Vt cols [784,832)
        int c = (b - 3392) * 256 + threadIdx.x;   // 0..212991
        short8 z = (short8){0,0,0,0,0,0,0,0};
        if (c < 114688) {                          // Q: 896 chunks per bh
            int bh = c / 896, j = c - bh * 896;
            *(short8*)&Qb[(bh * TPQ + TT) * 64 + j * 8] = z;
        } else if (c < 163840) {                   // K: 384 chunks per bh
            int c2 = c - 114688;
            int bh = c2 / 384, j = c2 - bh * 384;
            *(short8*)&Kb[(bh * TPK + TT) * 64 + j * 8] = z;
        } else {                                   // Vt: 384 chunks per bh (6 per d-row)
            int c3 = c - 163840;
            int bh = c3 / 384, j = c3 - bh * 384;
            int d = j / 6, m = j - d * 6;
            *(short8*)&Vt[(bh * 64 + d) * TPK + TT + m * 8] = z;
        }
    }
}

// ---------------- GEMM1: 128x128 tiles, 2-buffer gload_lds (R6-exact) ----------------
// R8/R9 lesson: 3-deep counted-vmcnt + 48KB LDS REGRESSED this kernel <42 -> 53 us
// (occupancy 4->3 blocks/CU + sched_barrier defeating compiler scheduling; guide m141).
// Reverted to the R6 structure: compiler-scheduled drain, 4 blocks/CU, 33KB LDS.
// n-fastest tile order + bijective XCD chunking kept (FETCH 146->13 MB, PMC-proven).
__global__ __launch_bounds__(256, 4) void gemm_qkv_kernel(
    const short* __restrict__ A, const short* __restrict__ Bt,
    const float* __restrict__ bq, const float* __restrict__ bk, const float* __restrict__ bv,
    short* __restrict__ Qb, short* __restrict__ Kb, short* __restrict__ Vt)
{
    __shared__ __align__(16) short smem[16640];   // staging dbuf 16384 shorts; Ct 16640
    short* As0 = smem;                             // [2][4096]  (128 x 32)
    short* Bs0 = smem + 8192;                      // [2][4096]

    const int orig = blockIdx.x;
    const int tile = (orig & 7) * 147 + (orig >> 3);   // XCD (orig%8) -> chunk [xcd*147, ...)
    const int m0 = (tile / 12) * 128, n0 = (tile % 12) * 128;  // n fastest: A-tile reuse
    const int tid = threadIdx.x;
    const int lane = tid & 63, w = tid >> 6;
    const int wr = w >> 1, wc = w & 1;
    const int l16 = lane & 15, quad = lane >> 4;

    const int srow = w * 32 + (lane >> 2);
    const int scol = (lane & 3) * 8;
    const short* Ag = A  + (size_t)(m0 + srow) * 512 + scol;
    const short* Bg = Bt + (size_t)(n0 + srow) * 512 + scol;
    short* Abase = As0 + w * 1024;
    short* Bbase = Bs0 + w * 1024;

    auto stage = [&](int it) {
        int b = it & 1;
        int ko = it * 32;
        gload_lds16(Ag + ko,            Abase + b * 4096);
        gload_lds16(Ag + ko + 16 * 512, Abase + b * 4096 + 512);
        gload_lds16(Bg + ko,            Bbase + b * 4096);
        gload_lds16(Bg + ko + 16 * 512, Bbase + b * 4096 + 512);
    };

    floatx4 acc[4][4];
    #pragma unroll
    for (int i = 0; i < 4; i++)
        #pragma unroll
        for (int j = 0; j < 4; j++)
            acc[i][j] = (floatx4){0.f, 0.f, 0.f, 0.f};

    stage(0);
    __syncthreads();

    for (int it = 0; it < 16; it++) {
        if (it < 15) stage(it + 1);
        const short* as = As0 + (it & 1) * 4096;
        const short* bs = Bs0 + (it & 1) * 4096;
        short8 af[4], bf[4];
        #pragma unroll
        for (int i = 0; i < 4; i++) {
            af[i] = *(const short8*)&as[(wr * 64 + i * 16 + l16) * 32 + quad * 8];
            bf[i] = *(const short8*)&bs[(wc * 64 + i * 16 + l16) * 32 + quad * 8];
        }
        #pragma unroll
        for (int mi = 0; mi < 4; mi++)
            #pragma unroll
            for (int ni = 0; ni < 4; ni++)
                acc[mi][ni] = __builtin_amdgcn_mfma_f32_16x16x32_bf16(af[mi], bf[ni], acc[mi][ni], 0, 0, 0);
        __syncthreads();
    }

    const int sel = n0 >> 9;   // 0=Q, 1=K, 2=V (uniform per block)
    if (sel == 2) {
        // V: direct 8B stores — acc rows are 4 consecutive t (4-aligned, never straddle b)
        #pragma unroll
        for (int mi = 0; mi < 4; mi++) {
            int m = m0 + wr * 64 + mi * 16 + quad * 4;
            int bb = m / TT, t = m - bb * TT;
            #pragma unroll
            for (int ni = 0; ni < 4; ni++) {
                int nn = (n0 + wc * 64 + ni * 16 + l16) & 511;
                int hh = nn >> 6, dd = nn & 63;
                float b = bv[nn];
                short4v pv;
                #pragma unroll
                for (int r = 0; r < 4; r++) pv[r] = f2bf(acc[mi][ni][r] + b);
                *(short4v*)&Vt[((size_t)(bb * HH + hh) * 64 + dd) * TPK + t] = pv;
            }
        }
    } else {
        short* Ct = smem;  // [128][130] bf16 (last mainloop barrier protects reuse)
        const float* bias = (sel == 0) ? bq : bk;
        #pragma unroll
        for (int mi = 0; mi < 4; mi++) {
            #pragma unroll
            for (int ni = 0; ni < 4; ni++) {
                int nl = wc * 64 + ni * 16 + l16;
                int nn = (n0 + nl) & 511;
                float b = bias[nn];
                #pragma unroll
                for (int r = 0; r < 4; r++) {
                    float v = acc[mi][ni][r] + b;
                    if (sel == 0) v *= 0.125f;
                    Ct[(wr * 64 + mi * 16 + quad * 4 + r) * 130 + nl] = f2bf(v);
                }
            }
        }
        __syncthreads();
        short* dst = (sel == 0) ? Qb : Kb;
        const int tp = (sel == 0) ? TPQ : TPK;
        int nl = lane * 2;
        int nn = (n0 + nl) & 511;
        int hh = nn >> 6, dd = nn & 63;
        #pragma unroll 4
        for (int rr = 0; rr < 32; rr++) {
            int ml = w * 32 + rr;
            int m = m0 + ml;
            int bb = m / TT, t = m - bb * TT;
            unsigned pv = *(const unsigned*)&Ct[ml * 130 + nl];
            *(unsigned*)&dst[((bb * HH + hh) * tp + t) * 64 + dd] = pv;
        }
    }
}

// ---------------- attention: 128-q blocks, each wave owns 32 q, full key range -------
// R9-verified (passed, absmax unchanged). vs R6 attn: half the staging traffic and
// barriers per unit q-work, no k-split LDS reduction. Kept; GEMMs reverted around it.
__global__ __launch_bounds__(256, 3) void attn_kernel(
    const short* __restrict__ Qb, const short* __restrict__ Kb, const short* __restrict__ Vt,
    short* __restrict__ ctx)
{
    // id = ((6-qb)*16 + bb)*8 + hh -> hh pins (b,h) to one XCD; qb descending = LPT
    const int g = blockIdx.x;
    const int low = g & 7, rest = g >> 3;
    const int qb = 6 - (rest >> 4);           // q-block 0..6 (128 rows each)
    const int bh = ((rest & 15) << 3) | low;
    const int bb = bh >> 3, hh = bh & 7;
    const int tid = threadIdx.x;
    const int lane = tid & 63, w = tid >> 6;
    const int l32 = lane & 31, hi = lane >> 5;
    const int r7 = l32 & 7;

    __shared__ __align__(16) short Ks[2][4096];   // [key][d], granule-XOR swizzle
    __shared__ __align__(16) short Vs[2][4096];   // [d][sigma(key)], granule-XOR swizzle

    const short* Kbase = Kb + (size_t)(bh * TPK) * 64;
    const short* Vbase = Vt + (size_t)(bh * 64) * TPK;

    const int srow = tid >> 3;          // 0..31
    const int sc8  = tid & 7;
    const int scol = sc8 * 8;
    const int ksw  = (sc8 ^ (srow & 7)) * 8;
    const int vg0  = (sc8 >> 1) * 2;
    const int vsw0 = ((vg0       ^ (srow & 7)) * 8) + (sc8 & 1) * 4;
    const int vsw1 = (((vg0 + 1) ^ (srow & 7)) * 8) + (sc8 & 1) * 4;

    short8 kreg[2], vreg[2];
    auto load_tile = [&](int kt) {
        #pragma unroll
        for (int p = 0; p < 2; p++) {
            int row = srow + p * 32;
            kreg[p] = *(const short8*)(Kbase + (kt * 64 + row) * 64 + scol);
            vreg[p] = *(const short8*)(Vbase + row * TPK + kt * 64 + scol);
        }
    };
    auto store_tile = [&](int b) {
        #pragma unroll
        for (int p = 0; p < 2; p++) {
            int ro = (srow + p * 32) * 64;
            *(short8*)&Ks[b][ro + ksw] = kreg[p];
            short4v v0, v1;
            #pragma unroll
            for (int i = 0; i < 4; i++) { v0[i] = vreg[p][i]; v1[i] = vreg[p][i + 4]; }
            *(short4v*)&Vs[b][ro + vsw0] = v0;
            *(short4v*)&Vs[b][ro + vsw1] = v1;
        }
    };

    const int q0   = qb * 128;
    const int q_lo = q0 + w * 32;                 // this wave's lowest q
    const int qg   = q_lo + l32;                  // this lane's q row (may be pad)
    const bool wreal = (q_lo < TT);
    const int q_top = (q0 + 127 < TT - 1) ? (q0 + 127) : (TT - 1);
    const int KT = (q_top >> 6) + 1;              // k-tiles needed by the block

    const short* Qrow = Qb + (size_t)(bh * TPQ + qg) * 64;
    short8 qf[4];
    #pragma unroll
    for (int d = 0; d < 4; d++) qf[d] = *(const short8*)(Qrow + d * 16 + hi * 8);

    floatx16 accO[2];
    #pragma unroll
    for (int dt = 0; dt < 2; dt++)
        #pragma unroll
        for (int i = 0; i < 16; i++) accO[dt][i] = 0.f;
    float accL = 0.f;

    load_tile(0);
    store_tile(0);

    for (int kt = 0; kt < KT; kt++) {
        const int cb = kt & 1;
        if (kt < KT - 1) load_tile(kt + 1);   // prefetch into regs, overlapped
        __syncthreads();                       // staging for kt visible
        if (wreal) {
            #pragma unroll
            for (int kh = 0; kh < 2; kh++) {
                const int kbase = kt * 64 + kh * 32;
                if (kbase > q_lo + 31) continue;   // wave-uniform: fully masked half
                floatx16 z;
                #pragma unroll
                for (int i = 0; i < 16; i++) z[i] = 0.f;
                #pragma unroll
                for (int d = 0; d < 4; d++) {
                    short8 kf = *(const short8*)&Ks[cb][(kh * 32 + l32) * 64 + (((d * 2 + hi) ^ r7) * 8)];
                    z = __builtin_amdgcn_mfma_f32_32x32x16_bf16(kf, qf[d], z, 0, 0, 0);
                }
                float p[16];
                #pragma unroll
                for (int r = 0; r < 16; r++) p[r] = __expf(z[r]);
                if (kbase + 31 > q_lo) {          // partial: causal mask (kills pad keys too)
                    #pragma unroll
                    for (int r = 0; r < 16; r++) {
                        int keyg = kbase + (r & 3) + 8 * (r >> 2) + 4 * hi;
                        if (keyg > qg) p[r] = 0.f;
                    }
                }
                #pragma unroll
                for (int r = 0; r < 16; r++) accL += p[r];
                #pragma unroll
                for (int s = 0; s < 2; s++) {
                    uint4v pw;
                    #pragma unroll
                    for (int jj = 0; jj < 4; jj++)
                        pw[jj] = cvtpk_bf16(p[8 * s + 2 * jj], p[8 * s + 2 * jj + 1]);
                    short8 pb = __builtin_bit_cast(short8, pw);
                    #pragma unroll
                    for (int dt = 0; dt < 2; dt++) {
                        short8 vf = *(const short8*)&Vs[cb][(dt * 32 + l32) * 64 + (((kh * 4 + s * 2 + hi) ^ r7) * 8)];
                        accO[dt] = __builtin_amdgcn_mfma_f32_32x32x16_bf16(vf, pb, accO[dt], 0, 0, 0);
                    }
                }
            }
        }
        if (kt < KT - 1) store_tile((kt + 1) & 1);   // all waves past this iter's barrier
    }

    // epilogue: combine hi-halves' row sums (lanes l32 / l32+32 share q), normalize, store
    float Lt = accL + __shfl_xor(accL, 32, 64);
    if (wreal && qg < TT) {
        float inv = 1.f / Lt;
        short* crow = ctx + (size_t)(bb * TT + qg) * 512 + hh * 64;
        #pragma unroll
        for (int dt = 0; dt < 2; dt++)
            #pragma unroll
            for (int g4 = 0; g4 < 4; g4++) {
                short4v pv;
                #pragma unroll
                for (int r4 = 0; r4 < 4; r4++) pv[r4] = f2bf(accO[dt][g4 * 4 + r4] * inv);
                *(short4v*)&crow[dt * 32 + g4 * 8 + 4 * hi] = pv;
            }
    }
}

// ---------------- GEMM2: ctx @ Wo + bo -> out fp32, 2-buffer gload_lds (R6-exact) ----
__global__ __launch_bounds__(256, 4) void gemm_out_kernel(
    const short* __restrict__ A, const short* __restrict__ Bt,
    const float* __restrict__ bo, float* __restrict__ out)
{
    __shared__ __align__(16) short smem[16384];
    short* As0 = smem;
    short* Bs0 = smem + 8192;

    const int orig = blockIdx.x;
    const int tile = (orig & 7) * 49 + (orig >> 3);    // 392 = 8*49, bijective
    const int m0 = (tile >> 2) * 128, n0 = (tile & 3) * 128;  // n fastest: ctx-tile reuse
    const int tid = threadIdx.x;
    const int lane = tid & 63, w = tid >> 6;
    const int wr = w >> 1, wc = w & 1;
    const int l16 = lane & 15, quad = lane >> 4;

    const int srow = w * 32 + (lane >> 2);
    const int scol = (lane & 3) * 8;
    const short* Ag = A  + (size_t)(m0 + srow) * 512 + scol;
    const short* Bg = Bt + (size_t)(n0 + srow) * 512 + scol;
    short* Abase = As0 + w * 1024;
    short* Bbase = Bs0 + w * 1024;

    auto stage = [&](int it) {
        int b = it & 1;
        int ko = it * 32;
        gload_lds16(Ag + ko,            Abase + b * 4096);
        gload_lds16(Ag + ko + 16 * 512, Abase + b * 4096 + 512);
        gload_lds16(Bg + ko,            Bbase + b * 4096);
        gload_lds16(Bg + ko + 16 * 512, Bbase + b * 4096 + 512);
    };

    floatx4 acc[4][4];
    #pragma unroll
    for (int i = 0; i < 4; i++)
        #pragma unroll
        for (int j = 0; j < 4; j++)
            acc[i][j] = (floatx4){0.f, 0.f, 0.f, 0.f};

    stage(0);
    __syncthreads();

    for (int it = 0; it < 16; it++) {
        if (it < 15) stage(it + 1);
        const short* as = As0 + (it & 1) * 4096;
        const short* bs = Bs0 + (it & 1) * 4096;
        short8 af[4], bf[4];
        #pragma unroll
        for (int i = 0; i < 4; i++) {
            af[i] = *(const short8*)&as[(wr * 64 + i * 16 + l16) * 32 + quad * 8];
            bf[i] = *(const short8*)&bs[(wc * 64 + i * 16 + l16) * 32 + quad * 8];
        }
        #pragma unroll
        for (int mi = 0; mi < 4; mi++)
            #pragma unroll
            for (int ni = 0; ni < 4; ni++)
                acc[mi][ni] = __builtin_amdgcn_mfma_f32_16x16x32_bf16(af[mi], bf[ni], acc[mi][ni], 0, 0, 0);
        __syncthreads();
    }

    #pragma unroll
    for (int mi = 0; mi < 4; mi++) {
        #pragma unroll
        for (int ni = 0; ni < 4; ni++) {
            int n = n0 + wc * 64 + ni * 16 + l16;
            float bias = bo[n];
            #pragma unroll
            for (int r = 0; r < 4; r++) {
                int m = m0 + wr * 64 + mi * 16 + quad * 4 + r;
                out[(size_t)m * 512 + n] = acc[mi][ni][r] + bias;
            }
        }
    }
}

extern "C" void kernel_launch(void* const* d_in, const int* in_sizes, int n_in,
                              void* d_out, int out_size, void* d_ws, size_t ws_size,
                              hipStream_t stream) {
    const float* x  = (const float*)d_in[0];
    const float* Wq = (const float*)d_in[1];
    const float* bq = (const float*)d_in[2];
    const float* Wk = (const float*)d_in[3];
    const float* bk = (const float*)d_in[4];
    const float* Wv = (const float*)d_in[5];
    const float* bv = (const float*)d_in[6];
    const float* Wo = (const float*)d_in[7];
    const float* bo = (const float*)d_in[8];
    float* out = (float*)d_out;

    char* ws = (char*)d_ws;
    size_t off = 0;
    auto alloc = [&](size_t bytes) -> void* {
        void* p = ws + off;
        off += (bytes + 255) & ~(size_t)255;
        return p;
    };
    short* xb    = (short*)alloc((size_t)BT * EE * 2);        // x bf16
    short* wqkvt = (short*)alloc((size_t)1536 * 512 * 2);     // Wqkv^T bf16
    short* wot   = (short*)alloc((size_t)512 * 512 * 2);      // Wo^T bf16
    short* Qb    = (short*)alloc((size_t)BB * HH * TPQ * DD * 2);
    short* Kb    = (short*)alloc((size_t)BB * HH * TPK * DD * 2);
    short* Vtb   = (short*)alloc((size_t)BB * HH * DD * TPK * 2);
    short* ctxb  = (short*)alloc((size_t)BT * EE * 2);

    prep_kernel<<<4224, 256, 0, stream>>>(x, xb, Wq, Wk, Wv, wqkvt, Wo, wot, Qb, Kb, Vtb);
    gemm_qkv_kernel<<<1176, 256, 0, stream>>>(xb, wqkvt, bq, bk, bv, Qb, Kb, Vtb);
    attn_kernel<<<896, 256, 0, stream>>>(Qb, Kb, Vtb, ctxb);
    gemm_out_kernel<<<392, 256, 0, stream>>>(ctxb, wot, bo, out);
}